// Round 1
// baseline (618.225 us; speedup 1.0000x reference)
//
#include <hip/hip_runtime.h>

// ---------------------------------------------------------------------------
// 2-layer GAT (PyG GATConv semantics), fp32, MI355X.
// Pipeline per launch:
//   CSR build (hist -> scan -> scatter)   [edges identical every call, but ws
//                                          is re-poisoned, so rebuild each time]
//   GEMM1 x@W1 -> h                [N,256]
//   k_att: a_src/a_dst from h      [N,4]
//   k_aggr<1>: segment-softmax aggregation + bias + relu -> hb [N,256]
//   GEMM2 hb@W2 -> h
//   k_att: a_src/a_dst
//   k_aggr<2>: aggregation, head-mean, bias, relu, softmax -> out [N,64]
// ---------------------------------------------------------------------------

__global__ __launch_bounds__(256)
void k_hist(const int* __restrict__ dstv, int* __restrict__ cnt, int E) {
  int i = blockIdx.x * 256 + threadIdx.x;
  if (i < E) atomicAdd(&cnt[dstv[i]], 1);
}

__global__ __launch_bounds__(256)
void k_scan_local(const int* __restrict__ cnt, int* __restrict__ rowptr,
                  int* __restrict__ partials, int N) {
  __shared__ int sm[256];
  int gid = blockIdx.x * 256 + threadIdx.x;
  int v = (gid < N) ? cnt[gid] : 0;
  sm[threadIdx.x] = v;
  __syncthreads();
  for (int off = 1; off < 256; off <<= 1) {
    int t = (threadIdx.x >= (unsigned)off) ? sm[threadIdx.x - off] : 0;
    __syncthreads();
    sm[threadIdx.x] += t;
    __syncthreads();
  }
  if (gid < N) rowptr[gid] = sm[threadIdx.x] - v;  // exclusive
  if (threadIdx.x == 255) partials[blockIdx.x] = sm[255];
}

__global__ __launch_bounds__(256)
void k_scan_part(int* __restrict__ partials, int nb) {
  __shared__ int sm[256];
  int t = threadIdx.x;
  int v = (t < nb) ? partials[t] : 0;
  sm[t] = v;
  __syncthreads();
  for (int off = 1; off < 256; off <<= 1) {
    int u = (t >= off) ? sm[t - off] : 0;
    __syncthreads();
    sm[t] += u;
    __syncthreads();
  }
  if (t < nb) partials[t] = sm[t] - v;  // exclusive
}

__global__ __launch_bounds__(256)
void k_scan_add(int* __restrict__ rowptr, const int* __restrict__ partials,
                int* __restrict__ cursor, int N, int E) {
  int gid = blockIdx.x * 256 + threadIdx.x;
  if (gid < N) {
    int rp = rowptr[gid] + partials[blockIdx.x];
    rowptr[gid] = rp;
    cursor[gid] = rp;
  }
  if (gid == 0) rowptr[N] = E;
}

__global__ __launch_bounds__(256)
void k_scatter(const int* __restrict__ srcv, const int* __restrict__ dstv,
               int* __restrict__ cursor, int* __restrict__ col, int E) {
  int i = blockIdx.x * 256 + threadIdx.x;
  if (i < E) {
    int p = atomicAdd(&cursor[dstv[i]], 1);
    col[p] = srcv[i];
  }
}

// ---------------------------------------------------------------------------
// fp32 GEMM: C[N,256] = A[N,K] @ W[K,256].  64x64 block tile, 16x16 threads,
// 4x4 microtile, K-tile 16. As padded to 17 to keep LDS reads conflict-light.
// ---------------------------------------------------------------------------
__global__ __launch_bounds__(256)
void k_gemm(const float* __restrict__ A, const float* __restrict__ W,
            float* __restrict__ C, int Nrows, int K) {
  __shared__ float As[64][17];
  __shared__ float Ws[16][64];
  const int tx = threadIdx.x & 15;
  const int ty = threadIdx.x >> 4;
  const int row0 = blockIdx.x * 64;
  const int col0 = blockIdx.y * 64;
  const int lr = threadIdx.x >> 2;        // 0..63 rows of A tile
  const int lk = (threadIdx.x & 3) * 4;   // 0,4,8,12 k within tile
  float acc[4][4] = {};
  for (int k0 = 0; k0 < K; k0 += 16) {
    int gr = row0 + lr;
    float4 av = make_float4(0.f, 0.f, 0.f, 0.f);
    if (gr < Nrows) av = *(const float4*)(A + (size_t)gr * K + k0 + lk);
    As[lr][lk + 0] = av.x; As[lr][lk + 1] = av.y;
    As[lr][lk + 2] = av.z; As[lr][lk + 3] = av.w;
#pragma unroll
    for (int i = 0; i < 4; i++) {
      int e = threadIdx.x + i * 256;
      int kw = e >> 6, c = e & 63;
      Ws[kw][c] = W[(size_t)(k0 + kw) * 256 + col0 + c];
    }
    __syncthreads();
#pragma unroll
    for (int kk = 0; kk < 16; kk++) {
      float a0 = As[ty * 4 + 0][kk];
      float a1 = As[ty * 4 + 1][kk];
      float a2 = As[ty * 4 + 2][kk];
      float a3 = As[ty * 4 + 3][kk];
      float4 b = *(const float4*)(&Ws[kk][tx * 4]);
      acc[0][0] += a0 * b.x; acc[0][1] += a0 * b.y; acc[0][2] += a0 * b.z; acc[0][3] += a0 * b.w;
      acc[1][0] += a1 * b.x; acc[1][1] += a1 * b.y; acc[1][2] += a1 * b.z; acc[1][3] += a1 * b.w;
      acc[2][0] += a2 * b.x; acc[2][1] += a2 * b.y; acc[2][2] += a2 * b.z; acc[2][3] += a2 * b.w;
      acc[3][0] += a3 * b.x; acc[3][1] += a3 * b.y; acc[3][2] += a3 * b.z; acc[3][3] += a3 * b.w;
    }
    __syncthreads();
  }
#pragma unroll
  for (int i = 0; i < 4; i++) {
    int gr = row0 + ty * 4 + i;
    if (gr < Nrows) {
      *(float4*)(C + (size_t)gr * 256 + col0 + tx * 4) =
          make_float4(acc[i][0], acc[i][1], acc[i][2], acc[i][3]);
    }
  }
}

// ---------------------------------------------------------------------------
// a_src[n][h] = sum_c h[n][h*64+c]*att_src[h][c]; same for a_dst.
// One wave per node; lane l handles 4 channels at offset 4l; 16-lane groups
// map to heads.
// ---------------------------------------------------------------------------
__global__ __launch_bounds__(256)
void k_att(const float* __restrict__ h, const float* __restrict__ att_s,
           const float* __restrict__ att_d, float* __restrict__ a_s,
           float* __restrict__ a_d, int N) {
  int node = (int)((blockIdx.x * 256u + threadIdx.x) >> 6);
  int lane = threadIdx.x & 63;
  if (node >= N) return;
  float4 hv = *(const float4*)(h + (size_t)node * 256 + lane * 4);
  float4 vs = *(const float4*)(att_s + lane * 4);
  float4 vd = *(const float4*)(att_d + lane * 4);
  float ps = hv.x * vs.x + hv.y * vs.y + hv.z * vs.z + hv.w * vs.w;
  float pd = hv.x * vd.x + hv.y * vd.y + hv.z * vd.z + hv.w * vd.w;
  for (int off = 8; off >= 1; off >>= 1) {
    ps += __shfl_xor(ps, off);
    pd += __shfl_xor(pd, off);
  }
  if ((lane & 15) == 0) {
    int head = lane >> 4;
    a_s[(size_t)node * 4 + head] = ps;
    a_d[(size_t)node * 4 + head] = pd;
  }
}

// ---------------------------------------------------------------------------
// Segment-softmax aggregation, one wave per dst node. Lane l owns channels
// [4l,4l+3] (head = l>>4). Edges processed in chunks of 64 with online
// softmax (running max m, denom d per head).
// LAYER 1: out = relu(acc/denom + b1), [N,256].
// LAYER 2: head-mean, +b2, relu, softmax over 64 channels -> [N,64].
// ---------------------------------------------------------------------------
template <int LAYER>
__global__ __launch_bounds__(256)
void k_aggr(const float* __restrict__ hsrc, const int* __restrict__ rowptr,
            const int* __restrict__ col, const float* __restrict__ a_s,
            const float* __restrict__ a_d, const float* __restrict__ bias,
            float* __restrict__ outp, int N) {
  int node = (int)((blockIdx.x * 256u + threadIdx.x) >> 6);
  int lane = threadIdx.x & 63;
  if (node >= N) return;
  int beg = rowptr[node], end = rowptr[node + 1];
  int head = lane >> 4;
  const float4 adst = *(const float4*)(a_d + (size_t)node * 4);

  float m0 = -3e38f, m1 = -3e38f, m2 = -3e38f, m3 = -3e38f;
  float d0 = 0.f, d1 = 0.f, d2 = 0.f, d3 = 0.f;
  float4 acc = make_float4(0.f, 0.f, 0.f, 0.f);

  for (int c0 = beg; c0 < end; c0 += 64) {
    int nc = min(64, end - c0);
    int s = 0;
    float e0 = -3e38f, e1 = -3e38f, e2 = -3e38f, e3 = -3e38f;
    if (lane < nc) {
      s = col[c0 + lane];
      float4 asr = *(const float4*)(a_s + (size_t)s * 4);
      e0 = asr.x + adst.x; e0 = e0 > 0.f ? e0 : 0.2f * e0;
      e1 = asr.y + adst.y; e1 = e1 > 0.f ? e1 : 0.2f * e1;
      e2 = asr.z + adst.z; e2 = e2 > 0.f ? e2 : 0.2f * e2;
      e3 = asr.w + adst.w; e3 = e3 > 0.f ? e3 : 0.2f * e3;
    }
    // chunk max per head across the wave
    float c0m = e0, c1m = e1, c2m = e2, c3m = e3;
    for (int off = 32; off; off >>= 1) {
      c0m = fmaxf(c0m, __shfl_xor(c0m, off));
      c1m = fmaxf(c1m, __shfl_xor(c1m, off));
      c2m = fmaxf(c2m, __shfl_xor(c2m, off));
      c3m = fmaxf(c3m, __shfl_xor(c3m, off));
    }
    float nm0 = fmaxf(m0, c0m), nm1 = fmaxf(m1, c1m);
    float nm2 = fmaxf(m2, c2m), nm3 = fmaxf(m3, c3m);
    float sc0 = __expf(m0 - nm0), sc1 = __expf(m1 - nm1);
    float sc2 = __expf(m2 - nm2), sc3 = __expf(m3 - nm3);
    float p0 = 0.f, p1 = 0.f, p2 = 0.f, p3 = 0.f;
    if (lane < nc) {
      p0 = __expf(e0 - nm0); p1 = __expf(e1 - nm1);
      p2 = __expf(e2 - nm2); p3 = __expf(e3 - nm3);
    }
    float s0 = p0, s1 = p1, s2 = p2, s3 = p3;
    for (int off = 32; off; off >>= 1) {
      s0 += __shfl_xor(s0, off);
      s1 += __shfl_xor(s1, off);
      s2 += __shfl_xor(s2, off);
      s3 += __shfl_xor(s3, off);
    }
    d0 = d0 * sc0 + s0; d1 = d1 * sc1 + s1;
    d2 = d2 * sc2 + s2; d3 = d3 * sc3 + s3;
    float asc = head == 0 ? sc0 : head == 1 ? sc1 : head == 2 ? sc2 : sc3;
    acc.x *= asc; acc.y *= asc; acc.z *= asc; acc.w *= asc;
    m0 = nm0; m1 = nm1; m2 = nm2; m3 = nm3;
    // message accumulation: gather h rows, weight by this lane's head prob
    for (int j = 0; j < nc; j++) {
      int sj = __shfl(s, j);
      float w0 = __shfl(p0, j), w1 = __shfl(p1, j);
      float w2 = __shfl(p2, j), w3 = __shfl(p3, j);
      float w = head == 0 ? w0 : head == 1 ? w1 : head == 2 ? w2 : w3;
      float4 hv = *(const float4*)(hsrc + (size_t)sj * 256 + lane * 4);
      acc.x += w * hv.x; acc.y += w * hv.y;
      acc.z += w * hv.z; acc.w += w * hv.w;
    }
  }

  float dh = head == 0 ? d0 : head == 1 ? d1 : head == 2 ? d2 : d3;
  float inv = 1.0f / dh;  // deg>=1 (self-loop) => dh>=1
  float4 v = make_float4(acc.x * inv, acc.y * inv, acc.z * inv, acc.w * inv);

  if (LAYER == 1) {
    float4 b4 = *(const float4*)(bias + lane * 4);
    v.x = fmaxf(v.x + b4.x, 0.f);
    v.y = fmaxf(v.y + b4.y, 0.f);
    v.z = fmaxf(v.z + b4.z, 0.f);
    v.w = fmaxf(v.w + b4.w, 0.f);
    *(float4*)(outp + (size_t)node * 256 + lane * 4) = v;
  } else {
    // mean over heads: butterfly across the 4 head groups (xor 16, 32)
    v.x += __shfl_xor(v.x, 16); v.y += __shfl_xor(v.y, 16);
    v.z += __shfl_xor(v.z, 16); v.w += __shfl_xor(v.w, 16);
    v.x += __shfl_xor(v.x, 32); v.y += __shfl_xor(v.y, 32);
    v.z += __shfl_xor(v.z, 32); v.w += __shfl_xor(v.w, 32);
    int c4 = (lane & 15) * 4;
    float4 b4 = *(const float4*)(bias + c4);
    v.x = fmaxf(v.x * 0.25f + b4.x, 0.f);
    v.y = fmaxf(v.y * 0.25f + b4.y, 0.f);
    v.z = fmaxf(v.z * 0.25f + b4.z, 0.f);
    v.w = fmaxf(v.w * 0.25f + b4.w, 0.f);
    // softmax over 64 channels held on 16-lane groups
    float mx = fmaxf(fmaxf(v.x, v.y), fmaxf(v.z, v.w));
    for (int off = 8; off >= 1; off >>= 1) mx = fmaxf(mx, __shfl_xor(mx, off));
    v.x = __expf(v.x - mx); v.y = __expf(v.y - mx);
    v.z = __expf(v.z - mx); v.w = __expf(v.w - mx);
    float sum = v.x + v.y + v.z + v.w;
    for (int off = 8; off >= 1; off >>= 1) sum += __shfl_xor(sum, off);
    float is = 1.0f / sum;
    v.x *= is; v.y *= is; v.z *= is; v.w *= is;
    if (lane < 16) *(float4*)(outp + (size_t)node * 64 + c4) = v;
  }
}

// ---------------------------------------------------------------------------

extern "C" void kernel_launch(void* const* d_in, const int* in_sizes, int n_in,
                              void* d_out, int out_size, void* d_ws, size_t ws_size,
                              hipStream_t stream) {
  const float* x   = (const float*)d_in[0];
  const int*   ei  = (const int*)d_in[1];
  const float* W1  = (const float*)d_in[2];
  const float* as1 = (const float*)d_in[3];
  const float* ad1 = (const float*)d_in[4];
  const float* b1  = (const float*)d_in[5];
  const float* W2  = (const float*)d_in[6];
  const float* as2 = (const float*)d_in[7];
  const float* ad2 = (const float*)d_in[8];
  const float* b2  = (const float*)d_in[9];
  float* out = (float*)d_out;

  const int N = in_sizes[0] / 128;
  const int E = in_sizes[1] / 2;
  const int* srcv = ei;
  const int* dstv = ei + E;

  // workspace layout (fp32 unless noted) — ~108 MB total
  float* h      = (float*)d_ws;                 // [N,256]
  float* hb     = h + (size_t)N * 256;          // [N,256]
  float* a_s    = hb + (size_t)N * 256;         // [N,4]
  float* a_d    = a_s + (size_t)N * 4;          // [N,4]
  int*   rowptr = (int*)(a_d + (size_t)N * 4);  // [N+1] (+pad)
  int*   cnt    = rowptr + (N + 4);             // [N]
  int*   cursor = cnt + N;                      // [N]
  int*   col    = cursor + N;                   // [E]
  int*   partials = col + E;                    // [<=256]

  const int nb = (N + 255) / 256;
  const int eb = (E + 255) / 256;

  hipMemsetAsync(cnt, 0, (size_t)N * 4, stream);
  k_hist<<<eb, 256, 0, stream>>>(dstv, cnt, E);
  k_scan_local<<<nb, 256, 0, stream>>>(cnt, rowptr, partials, N);
  k_scan_part<<<1, 256, 0, stream>>>(partials, nb);
  k_scan_add<<<nb, 256, 0, stream>>>(rowptr, partials, cursor, N, E);
  k_scatter<<<eb, 256, 0, stream>>>(srcv, dstv, cursor, col, E);

  dim3 gg((N + 63) / 64, 4);
  const int wb = (N + 3) / 4;  // wave-per-node kernels

  k_gemm<<<gg, 256, 0, stream>>>(x, W1, h, N, 128);
  k_att<<<wb, 256, 0, stream>>>(h, as1, ad1, a_s, a_d, N);
  k_aggr<1><<<wb, 256, 0, stream>>>(h, rowptr, col, a_s, a_d, b1, hb, N);
  k_gemm<<<gg, 256, 0, stream>>>(hb, W2, h, N, 256);
  k_att<<<wb, 256, 0, stream>>>(h, as2, ad2, a_s, a_d, N);
  k_aggr<2><<<wb, 256, 0, stream>>>(h, rowptr, col, a_s, a_d, b2, out, N);
}

// Round 2
// 613.507 us; speedup vs baseline: 1.0077x; 1.0077x over previous
//
#include <hip/hip_runtime.h>

// ---------------------------------------------------------------------------
// 2-layer GAT (PyG GATConv semantics), fp32, MI355X.
// R2: k_aggr — LDS-staged (src,weight) broadcast instead of 5 shfls/edge,
//     4x-unrolled gather for MLP.
//     k_gemm — 128x128 tile, 8x8 microtile, A transposed in LDS (b128 reads
//     only), B panel in registers from L2 (W is 256KB, L2-resident).
// ---------------------------------------------------------------------------

__global__ __launch_bounds__(256)
void k_hist(const int* __restrict__ dstv, int* __restrict__ cnt, int E) {
  int i = blockIdx.x * 256 + threadIdx.x;
  if (i < E) atomicAdd(&cnt[dstv[i]], 1);
}

__global__ __launch_bounds__(256)
void k_scan_local(const int* __restrict__ cnt, int* __restrict__ rowptr,
                  int* __restrict__ partials, int N) {
  __shared__ int sm[256];
  int gid = blockIdx.x * 256 + threadIdx.x;
  int v = (gid < N) ? cnt[gid] : 0;
  sm[threadIdx.x] = v;
  __syncthreads();
  for (int off = 1; off < 256; off <<= 1) {
    int t = (threadIdx.x >= (unsigned)off) ? sm[threadIdx.x - off] : 0;
    __syncthreads();
    sm[threadIdx.x] += t;
    __syncthreads();
  }
  if (gid < N) rowptr[gid] = sm[threadIdx.x] - v;  // exclusive
  if (threadIdx.x == 255) partials[blockIdx.x] = sm[255];
}

__global__ __launch_bounds__(256)
void k_scan_part(int* __restrict__ partials, int nb) {
  __shared__ int sm[256];
  int t = threadIdx.x;
  int v = (t < nb) ? partials[t] : 0;
  sm[t] = v;
  __syncthreads();
  for (int off = 1; off < 256; off <<= 1) {
    int u = (t >= off) ? sm[t - off] : 0;
    __syncthreads();
    sm[t] += u;
    __syncthreads();
  }
  if (t < nb) partials[t] = sm[t] - v;  // exclusive
}

__global__ __launch_bounds__(256)
void k_scan_add(int* __restrict__ rowptr, const int* __restrict__ partials,
                int* __restrict__ cursor, int N, int E) {
  int gid = blockIdx.x * 256 + threadIdx.x;
  if (gid < N) {
    int rp = rowptr[gid] + partials[blockIdx.x];
    rowptr[gid] = rp;
    cursor[gid] = rp;
  }
  if (gid == 0) rowptr[N] = E;
}

__global__ __launch_bounds__(256)
void k_scatter(const int* __restrict__ srcv, const int* __restrict__ dstv,
               int* __restrict__ cursor, int* __restrict__ col, int E) {
  int i = blockIdx.x * 256 + threadIdx.x;
  if (i < E) {
    int p = atomicAdd(&cursor[dstv[i]], 1);
    col[p] = srcv[i];
  }
}

// ---------------------------------------------------------------------------
// fp32 GEMM: C[N,256] = A[N,K] @ W[K,256]. 128x128 block tile, 16x16 threads,
// 8x8 microtile, K-tile 8. A transposed in LDS (pad 132 -> max 2-way, free).
// B panel held in registers, loaded directly from global (L2-resident W).
// Inner loop: 2x ds_read_b128 per kk + 64 FMA -> VALU-bound.
// ---------------------------------------------------------------------------
__global__ __launch_bounds__(256)
void k_gemm(const float* __restrict__ A, const float* __restrict__ W,
            float* __restrict__ C, int Nrows, int K) {
  __shared__ float At[8][132];
  const int tx = threadIdx.x & 15;        // col group: cols tx*8..tx*8+7
  const int ty = threadIdx.x >> 4;        // row group: rows ty*8..ty*8+7
  const int row0 = blockIdx.x * 128;
  const int col0 = blockIdx.y * 128;
  const int arow = threadIdx.x >> 1;      // 0..127
  const int akk  = (threadIdx.x & 1) * 4; // 0 or 4

  float acc[8][8] = {};

  for (int k0 = 0; k0 < K; k0 += 8) {
    // ---- load B panel (8 x 128) into registers straight from global/L2
    float breg[8][8];
#pragma unroll
    for (int kk = 0; kk < 8; kk++) {
      const float* wp = W + (size_t)(k0 + kk) * 256 + col0 + tx * 8;
      float4 b0 = *(const float4*)(wp);
      float4 b1 = *(const float4*)(wp + 4);
      breg[kk][0] = b0.x; breg[kk][1] = b0.y; breg[kk][2] = b0.z; breg[kk][3] = b0.w;
      breg[kk][4] = b1.x; breg[kk][5] = b1.y; breg[kk][6] = b1.z; breg[kk][7] = b1.w;
    }
    // ---- stage A tile (128 rows x 8 k) transposed into LDS
    int gr = row0 + arow;
    float4 av = make_float4(0.f, 0.f, 0.f, 0.f);
    if (gr < Nrows) av = *(const float4*)(A + (size_t)gr * K + k0 + akk);
    At[akk + 0][arow] = av.x;
    At[akk + 1][arow] = av.y;
    At[akk + 2][arow] = av.z;
    At[akk + 3][arow] = av.w;
    __syncthreads();

#pragma unroll
    for (int kk = 0; kk < 8; kk++) {
      float4 a0 = *(const float4*)(&At[kk][ty * 8]);
      float4 a1 = *(const float4*)(&At[kk][ty * 8 + 4]);
      float ar[8] = {a0.x, a0.y, a0.z, a0.w, a1.x, a1.y, a1.z, a1.w};
#pragma unroll
      for (int i = 0; i < 8; i++)
#pragma unroll
        for (int j = 0; j < 8; j++)
          acc[i][j] += ar[i] * breg[kk][j];
    }
    __syncthreads();
  }

#pragma unroll
  for (int i = 0; i < 8; i++) {
    int gr = row0 + ty * 8 + i;
    if (gr < Nrows) {
      float* cp = C + (size_t)gr * 256 + col0 + tx * 8;
      *(float4*)(cp)     = make_float4(acc[i][0], acc[i][1], acc[i][2], acc[i][3]);
      *(float4*)(cp + 4) = make_float4(acc[i][4], acc[i][5], acc[i][6], acc[i][7]);
    }
  }
}

// ---------------------------------------------------------------------------
// a_src[n][h] = sum_c h[n][h*64+c]*att_src[h][c]; same for a_dst.
// One wave per node; lane l handles 4 channels at offset 4l.
// ---------------------------------------------------------------------------
__global__ __launch_bounds__(256)
void k_att(const float* __restrict__ h, const float* __restrict__ att_s,
           const float* __restrict__ att_d, float* __restrict__ a_s,
           float* __restrict__ a_d, int N) {
  int node = (int)((blockIdx.x * 256u + threadIdx.x) >> 6);
  int lane = threadIdx.x & 63;
  if (node >= N) return;
  float4 hv = *(const float4*)(h + (size_t)node * 256 + lane * 4);
  float4 vs = *(const float4*)(att_s + lane * 4);
  float4 vd = *(const float4*)(att_d + lane * 4);
  float ps = hv.x * vs.x + hv.y * vs.y + hv.z * vs.z + hv.w * vs.w;
  float pd = hv.x * vd.x + hv.y * vd.y + hv.z * vd.z + hv.w * vd.w;
  for (int off = 8; off >= 1; off >>= 1) {
    ps += __shfl_xor(ps, off);
    pd += __shfl_xor(pd, off);
  }
  if ((lane & 15) == 0) {
    int head = lane >> 4;
    a_s[(size_t)node * 4 + head] = ps;
    a_d[(size_t)node * 4 + head] = pd;
  }
}

// ---------------------------------------------------------------------------
// Segment-softmax aggregation, one wave per dst node. Lane l owns channels
// [4l,4l+3] (head = l>>4). Edges in chunks of 64 with online softmax.
// Per-chunk (src, per-head weight) staged in LDS: the j-loop costs
// 2 ds_read_b32 + 1 global b128 + 4 FMA per edge (was 5 shfls).
// ---------------------------------------------------------------------------
template <int LAYER>
__global__ __launch_bounds__(256)
void k_aggr(const float* __restrict__ hsrc, const int* __restrict__ rowptr,
            const int* __restrict__ col, const float* __restrict__ a_s,
            const float* __restrict__ a_d, const float* __restrict__ bias,
            float* __restrict__ outp, int N) {
  __shared__ int   s_sh[4][64];
  __shared__ float w_sh[4][256];
  const int wv = threadIdx.x >> 6;
  const int lane = threadIdx.x & 63;
  int node = blockIdx.x * 4 + wv;
  if (node >= N) return;
  int beg = rowptr[node], end = rowptr[node + 1];
  int head = lane >> 4;
  const float4 adst = *(const float4*)(a_d + (size_t)node * 4);

  float m0 = -3e38f, m1 = -3e38f, m2 = -3e38f, m3 = -3e38f;
  float d0 = 0.f, d1 = 0.f, d2 = 0.f, d3 = 0.f;
  float4 acc = make_float4(0.f, 0.f, 0.f, 0.f);

  for (int c0 = beg; c0 < end; c0 += 64) {
    int nc = min(64, end - c0);
    int s = 0;
    float e0 = -3e38f, e1 = -3e38f, e2 = -3e38f, e3 = -3e38f;
    if (lane < nc) {
      s = col[c0 + lane];
      float4 asr = *(const float4*)(a_s + (size_t)s * 4);
      e0 = asr.x + adst.x; e0 = e0 > 0.f ? e0 : 0.2f * e0;
      e1 = asr.y + adst.y; e1 = e1 > 0.f ? e1 : 0.2f * e1;
      e2 = asr.z + adst.z; e2 = e2 > 0.f ? e2 : 0.2f * e2;
      e3 = asr.w + adst.w; e3 = e3 > 0.f ? e3 : 0.2f * e3;
    }
    float c0m = e0, c1m = e1, c2m = e2, c3m = e3;
    for (int off = 32; off; off >>= 1) {
      c0m = fmaxf(c0m, __shfl_xor(c0m, off));
      c1m = fmaxf(c1m, __shfl_xor(c1m, off));
      c2m = fmaxf(c2m, __shfl_xor(c2m, off));
      c3m = fmaxf(c3m, __shfl_xor(c3m, off));
    }
    float nm0 = fmaxf(m0, c0m), nm1 = fmaxf(m1, c1m);
    float nm2 = fmaxf(m2, c2m), nm3 = fmaxf(m3, c3m);
    float sc0 = __expf(m0 - nm0), sc1 = __expf(m1 - nm1);
    float sc2 = __expf(m2 - nm2), sc3 = __expf(m3 - nm3);
    float p0 = 0.f, p1 = 0.f, p2 = 0.f, p3 = 0.f;
    if (lane < nc) {
      p0 = __expf(e0 - nm0); p1 = __expf(e1 - nm1);
      p2 = __expf(e2 - nm2); p3 = __expf(e3 - nm3);
    }
    float s0 = p0, s1 = p1, s2 = p2, s3 = p3;
    for (int off = 32; off; off >>= 1) {
      s0 += __shfl_xor(s0, off);
      s1 += __shfl_xor(s1, off);
      s2 += __shfl_xor(s2, off);
      s3 += __shfl_xor(s3, off);
    }
    d0 = d0 * sc0 + s0; d1 = d1 * sc1 + s1;
    d2 = d2 * sc2 + s2; d3 = d3 * sc3 + s3;
    float asc = head == 0 ? sc0 : head == 1 ? sc1 : head == 2 ? sc2 : sc3;
    acc.x *= asc; acc.y *= asc; acc.z *= asc; acc.w *= asc;
    m0 = nm0; m1 = nm1; m2 = nm2; m3 = nm3;

    // stage (src, per-head weight) for wave-wide broadcast
    s_sh[wv][lane] = s;
    *(float4*)(&w_sh[wv][lane * 4]) = make_float4(p0, p1, p2, p3);
    asm volatile("s_waitcnt lgkmcnt(0)" ::: "memory");

    const float* wrow = &w_sh[wv][head];
    const int*   srow = &s_sh[wv][0];
    int j = 0;
    for (; j + 4 <= nc; j += 4) {
      int sj0 = srow[j], sj1 = srow[j + 1], sj2 = srow[j + 2], sj3 = srow[j + 3];
      float w0 = wrow[4 * j], w1 = wrow[4 * j + 4];
      float w2 = wrow[4 * j + 8], w3 = wrow[4 * j + 12];
      float4 h0 = *(const float4*)(hsrc + (size_t)sj0 * 256 + lane * 4);
      float4 h1 = *(const float4*)(hsrc + (size_t)sj1 * 256 + lane * 4);
      float4 h2 = *(const float4*)(hsrc + (size_t)sj2 * 256 + lane * 4);
      float4 h3 = *(const float4*)(hsrc + (size_t)sj3 * 256 + lane * 4);
      acc.x += w0 * h0.x; acc.y += w0 * h0.y; acc.z += w0 * h0.z; acc.w += w0 * h0.w;
      acc.x += w1 * h1.x; acc.y += w1 * h1.y; acc.z += w1 * h1.z; acc.w += w1 * h1.w;
      acc.x += w2 * h2.x; acc.y += w2 * h2.y; acc.z += w2 * h2.z; acc.w += w2 * h2.w;
      acc.x += w3 * h3.x; acc.y += w3 * h3.y; acc.z += w3 * h3.z; acc.w += w3 * h3.w;
    }
    for (; j < nc; j++) {
      int sj = srow[j];
      float w = wrow[4 * j];
      float4 hv = *(const float4*)(hsrc + (size_t)sj * 256 + lane * 4);
      acc.x += w * hv.x; acc.y += w * hv.y;
      acc.z += w * hv.z; acc.w += w * hv.w;
    }
  }

  float dh = head == 0 ? d0 : head == 1 ? d1 : head == 2 ? d2 : d3;
  float inv = 1.0f / dh;  // deg>=1 (self-loop) => dh>=1
  float4 v = make_float4(acc.x * inv, acc.y * inv, acc.z * inv, acc.w * inv);

  if (LAYER == 1) {
    float4 b4 = *(const float4*)(bias + lane * 4);
    v.x = fmaxf(v.x + b4.x, 0.f);
    v.y = fmaxf(v.y + b4.y, 0.f);
    v.z = fmaxf(v.z + b4.z, 0.f);
    v.w = fmaxf(v.w + b4.w, 0.f);
    *(float4*)(outp + (size_t)node * 256 + lane * 4) = v;
  } else {
    v.x += __shfl_xor(v.x, 16); v.y += __shfl_xor(v.y, 16);
    v.z += __shfl_xor(v.z, 16); v.w += __shfl_xor(v.w, 16);
    v.x += __shfl_xor(v.x, 32); v.y += __shfl_xor(v.y, 32);
    v.z += __shfl_xor(v.z, 32); v.w += __shfl_xor(v.w, 32);
    int c4 = (lane & 15) * 4;
    float4 b4 = *(const float4*)(bias + c4);
    v.x = fmaxf(v.x * 0.25f + b4.x, 0.f);
    v.y = fmaxf(v.y * 0.25f + b4.y, 0.f);
    v.z = fmaxf(v.z * 0.25f + b4.z, 0.f);
    v.w = fmaxf(v.w * 0.25f + b4.w, 0.f);
    float mx = fmaxf(fmaxf(v.x, v.y), fmaxf(v.z, v.w));
    for (int off = 8; off >= 1; off >>= 1) mx = fmaxf(mx, __shfl_xor(mx, off));
    v.x = __expf(v.x - mx); v.y = __expf(v.y - mx);
    v.z = __expf(v.z - mx); v.w = __expf(v.w - mx);
    float sum = v.x + v.y + v.z + v.w;
    for (int off = 8; off >= 1; off >>= 1) sum += __shfl_xor(sum, off);
    float is = 1.0f / sum;
    v.x *= is; v.y *= is; v.z *= is; v.w *= is;
    if (lane < 16) *(float4*)(outp + (size_t)node * 64 + c4) = v;
  }
}

// ---------------------------------------------------------------------------

extern "C" void kernel_launch(void* const* d_in, const int* in_sizes, int n_in,
                              void* d_out, int out_size, void* d_ws, size_t ws_size,
                              hipStream_t stream) {
  const float* x   = (const float*)d_in[0];
  const int*   ei  = (const int*)d_in[1];
  const float* W1  = (const float*)d_in[2];
  const float* as1 = (const float*)d_in[3];
  const float* ad1 = (const float*)d_in[4];
  const float* b1  = (const float*)d_in[5];
  const float* W2  = (const float*)d_in[6];
  const float* as2 = (const float*)d_in[7];
  const float* ad2 = (const float*)d_in[8];
  const float* b2  = (const float*)d_in[9];
  float* out = (float*)d_out;

  const int N = in_sizes[0] / 128;
  const int E = in_sizes[1] / 2;
  const int* srcv = ei;
  const int* dstv = ei + E;

  float* h      = (float*)d_ws;                 // [N,256]
  float* hb     = h + (size_t)N * 256;          // [N,256]
  float* a_s    = hb + (size_t)N * 256;         // [N,4]
  float* a_d    = a_s + (size_t)N * 4;          // [N,4]
  int*   rowptr = (int*)(a_d + (size_t)N * 4);  // [N+1] (+pad)
  int*   cnt    = rowptr + (N + 4);             // [N]
  int*   cursor = cnt + N;                      // [N]
  int*   col    = cursor + N;                   // [E]
  int*   partials = col + E;                    // [<=256]

  const int nb = (N + 255) / 256;
  const int eb = (E + 255) / 256;

  hipMemsetAsync(cnt, 0, (size_t)N * 4, stream);
  k_hist<<<eb, 256, 0, stream>>>(dstv, cnt, E);
  k_scan_local<<<nb, 256, 0, stream>>>(cnt, rowptr, partials, N);
  k_scan_part<<<1, 256, 0, stream>>>(partials, nb);
  k_scan_add<<<nb, 256, 0, stream>>>(rowptr, partials, cursor, N, E);
  k_scatter<<<eb, 256, 0, stream>>>(srcv, dstv, cursor, col, E);

  dim3 gg((N + 127) / 128, 2);
  const int wb = (N + 3) / 4;  // wave-per-node kernels

  k_gemm<<<gg, 256, 0, stream>>>(x, W1, h, N, 128);
  k_att<<<wb, 256, 0, stream>>>(h, as1, ad1, a_s, a_d, N);
  k_aggr<1><<<wb, 256, 0, stream>>>(h, rowptr, col, a_s, a_d, b1, hb, N);
  k_gemm<<<gg, 256, 0, stream>>>(hb, W2, h, N, 256);
  k_att<<<wb, 256, 0, stream>>>(h, as2, ad2, a_s, a_d, N);
  k_aggr<2><<<wb, 256, 0, stream>>>(h, rowptr, col, a_s, a_d, b2, out, N);
}